// Round 1
// baseline (362.376 us; speedup 1.0000x reference)
//
#include <hip/hip_runtime.h>

#define BATCH 8
#define CH    16
#define IN_H  540
#define IN_W  960
#define OUT_H 1080
#define OUT_W 1920
#define OW4   (OUT_W / 4)   // 480 float4 per output row

// Gather formulation: every output element is written exactly once (no memset
// needed; harness poisons d_out so full coverage is required). For each output
// (b,c,oh,ow) find the unique input (h,w) that the reference scatter maps
// there, by forward-verifying candidate indices with the bit-identical fp32
// expression the reference uses.
__global__ __launch_bounds__(256) void ZeroUpsample_kernel(
    const float* __restrict__ in, const float* __restrict__ jitter,
    float* __restrict__ out, unsigned total_vec)
{
    unsigned idx = blockIdx.x * blockDim.x + threadIdx.x;
    if (idx >= total_vec) return;

    unsigned ow4 = idx % OW4;
    unsigned t   = idx / OW4;
    unsigned oh  = t % OUT_H;
    unsigned t2  = t / OUT_H;
    unsigned c   = t2 % CH;
    unsigned b   = t2 / CH;

    const float jy = jitter[2 * b + 0];
    const float jx = jitter[2 * b + 1];

    // ---- inverse row map: find h with clip(floor((h+0.5+jy)*2),0,OUT_H-1)==oh
    const int dy = (int)floorf(2.0f * jy);           // exact: *2 and floor are exact
    const int h0 = ((int)oh - 1 - dy) >> 1;          // analytic candidate (floor div)
    int ih = -1;
    #pragma unroll
    for (int d = -1; d <= 1; ++d) {
        int h = h0 + d;
        if (h < 0 || h >= IN_H) continue;
        int f = (int)floorf(((float)h + 0.5f + jy) * 2.0f);  // identical fp32 ops as ref
        f = f < 0 ? 0 : (f > OUT_H - 1 ? OUT_H - 1 : f);
        if (f == (int)oh) ih = h;                    // last match wins (np semantics)
    }

    float4 v = make_float4(0.0f, 0.0f, 0.0f, 0.0f);
    if (ih >= 0) {
        const int dx = (int)floorf(2.0f * jx);
        const int ow_base = (int)ow4 * 4;
        const float* __restrict__ inrow =
            in + (((size_t)b * CH + c) * IN_H + ih) * IN_W;
        float* vp = &v.x;
        #pragma unroll
        for (int k = 0; k < 4; ++k) {
            int ow = ow_base + k;
            int w0 = (ow - 1 - dx) >> 1;
            int iw = -1;
            #pragma unroll
            for (int d = -1; d <= 1; ++d) {
                int w = w0 + d;
                if (w < 0 || w >= IN_W) continue;
                int f = (int)floorf(((float)w + 0.5f + jx) * 2.0f);
                f = f < 0 ? 0 : (f > OUT_W - 1 ? OUT_W - 1 : f);
                if (f == ow) iw = w;
            }
            if (iw >= 0) vp[k] = inrow[iw];
        }
    }

    float4* __restrict__ outp =
        (float4*)(out + (((size_t)b * CH + c) * OUT_H + oh) * OUT_W);
    outp[ow4] = v;
}

extern "C" void kernel_launch(void* const* d_in, const int* in_sizes, int n_in,
                              void* d_out, int out_size, void* d_ws, size_t ws_size,
                              hipStream_t stream) {
    const float* in     = (const float*)d_in[0];   // [8,16,540,960] fp32
    const float* jitter = (const float*)d_in[1];   // [8,2,1,1] fp32
    float* out          = (float*)d_out;           // [8,16,1080,1920] fp32

    const unsigned total_vec = BATCH * CH * OUT_H * OW4;  // 66,355,200 float4s
    dim3 block(256);
    dim3 grid((total_vec + block.x - 1) / block.x);
    hipLaunchKernelGGL(ZeroUpsample_kernel, grid, block, 0, stream,
                       in, jitter, out, total_vec);
}

// Round 2
// 263.350 us; speedup vs baseline: 1.3760x; 1.3760x over previous
//
#include <hip/hip_runtime.h>

#define BATCH 8
#define CH    16
#define IN_H  540
#define IN_W  960
#define OUT_H 1080
#define OUT_W 1920
#define OW4   (OUT_W / 4)        // 480 float4 per output row
#define ROWS  8                  // output rows per block
#define NIT   ((ROWS * OW4) / 256)  // 15 iterations, exact

// Gather formulation with LDS-tabled inverse maps.
// The inverse row map depends only on (b,oh); the inverse column map only on
// (b,ow). Build them once per block in LDS (verified with the bit-identical
// fp32 forward expression the reference uses — proven absmax==0 in round 1),
// then the inner loop is ~20 VALU ops per coalesced float4 store.
__global__ __launch_bounds__(256) void ZeroUpsample_kernel(
    const float* __restrict__ in, const float* __restrict__ jitter,
    float* __restrict__ out)
{
    const int tid = threadIdx.x;
    const int b   = blockIdx.z;
    const int c   = blockIdx.y;
    const int oh0 = blockIdx.x * ROWS;

    const float jy = jitter[2 * b + 0];
    const float jx = jitter[2 * b + 1];
    const int dy = (int)floorf(2.0f * jy);   // exact: *2, floor
    const int dx = (int)floorf(2.0f * jx);

    __shared__ short iw_tab[OUT_W] __attribute__((aligned(8)));
    __shared__ short ih_tab[ROWS];

    // ---- column table: iw_tab[ow] = input col scattering to ow, or -1
    for (int ow = tid; ow < OUT_W; ow += 256) {
        int w0 = (ow - 1 - dx) >> 1;
        short iw = -1;
        #pragma unroll
        for (int d = -1; d <= 1; ++d) {
            int w = w0 + d;
            if (w < 0 || w >= IN_W) continue;
            int f = (int)floorf(((float)w + 0.5f + jx) * 2.0f);  // identical fp32 ops
            f = f < 0 ? 0 : (f > OUT_W - 1 ? OUT_W - 1 : f);
            if (f == ow) iw = (short)w;     // last match wins (np semantics)
        }
        iw_tab[ow] = iw;
    }
    // ---- row table for this block's 8 rows
    if (tid < ROWS) {
        int oh = oh0 + tid;
        int h0 = (oh - 1 - dy) >> 1;
        short ih = -1;
        #pragma unroll
        for (int d = -1; d <= 1; ++d) {
            int h = h0 + d;
            if (h < 0 || h >= IN_H) continue;
            int f = (int)floorf(((float)h + 0.5f + jy) * 2.0f);
            f = f < 0 ? 0 : (f > OUT_H - 1 ? OUT_H - 1 : f);
            if (f == oh) ih = (short)h;
        }
        ih_tab[tid] = ih;
    }
    __syncthreads();

    const float*  __restrict__ inbase  =
        in + ((size_t)(b * CH + c) * IN_H) * IN_W;
    float4* __restrict__ outbase =
        (float4*)(out + ((size_t)(b * CH + c) * OUT_H + oh0) * OUT_W);

    #pragma unroll
    for (int it = 0; it < NIT; ++it) {
        int pos = it * 256 + tid;
        int r   = pos / OW4;                 // const div -> magic mul
        int ow4 = pos - r * OW4;
        int ih  = ih_tab[r];
        float4 v = make_float4(0.f, 0.f, 0.f, 0.f);
        if (ih >= 0) {                       // mostly wave-uniform (whole row zero or not)
            const float* __restrict__ inrow = inbase + (size_t)ih * IN_W;
            short4 s = reinterpret_cast<const short4*>(iw_tab)[ow4];  // ds_read_b64
            if (s.x >= 0) v.x = inrow[s.x];
            if (s.y >= 0) v.y = inrow[s.y];
            if (s.z >= 0) v.z = inrow[s.z];
            if (s.w >= 0) v.w = inrow[s.w];
        }
        outbase[(size_t)r * OW4 + ow4] = v;  // coalesced 16B store
    }
}

extern "C" void kernel_launch(void* const* d_in, const int* in_sizes, int n_in,
                              void* d_out, int out_size, void* d_ws, size_t ws_size,
                              hipStream_t stream) {
    const float* in     = (const float*)d_in[0];   // [8,16,540,960] fp32
    const float* jitter = (const float*)d_in[1];   // [8,2,1,1] fp32
    float* out          = (float*)d_out;           // [8,16,1080,1920] fp32

    dim3 block(256);
    dim3 grid(OUT_H / ROWS, CH, BATCH);            // 135 x 16 x 8 = 17280 blocks
    hipLaunchKernelGGL(ZeroUpsample_kernel, grid, block, 0, stream,
                       in, jitter, out);
}

// Round 4
// 206.262 us; speedup vs baseline: 1.7569x; 1.2768x over previous
//
#include <hip/hip_runtime.h>

#define BATCH 8
#define CH    16
#define IN_H  540
#define IN_W  960
#define IN_W4 (IN_W / 4)      // 240 float4 per input row
#define OUT_H 1080
#define OUT_W 1920
#define OW4   (OUT_W / 4)     // 480 float4 per output row
#define ROWS  8               // output rows per block
#define SLOTS 7               // max distinct input rows a block can touch (proven bound)
#define NIT   ((ROWS * OW4) / 256)  // 15 iterations, exact

typedef float floatx4 __attribute__((ext_vector_type(4)));  // native vec for nontemporal builtin

// Gather with LDS-tabled inverse maps + LDS-staged input rows.
// Inverse maps are forward-verified with the bit-identical fp32 expression the
// reference uses (absmax==0 in rounds 1-2). Input rows staged into LDS via
// coalesced float4 loads (was stride-8B scalar gathers); output written with
// nontemporal stores so the 1.06 GB write stream doesn't evict the 246 MB
// input from Infinity Cache.
__global__ __launch_bounds__(256) void ZeroUpsample_kernel(
    const float* __restrict__ in, const float* __restrict__ jitter,
    float* __restrict__ out)
{
    const int tid = threadIdx.x;
    const int b   = blockIdx.z;
    const int c   = blockIdx.y;
    const int oh0 = blockIdx.x * ROWS;

    const float jy = jitter[2 * b + 0];
    const float jx = jitter[2 * b + 1];
    const int dy = (int)floorf(2.0f * jy);   // exact: *2, floor
    const int dx = (int)floorf(2.0f * jx);

    __shared__ float srows[SLOTS][IN_W];                        // 26880 B
    __shared__ short iw_tab[OUT_W] __attribute__((aligned(8))); // 3840 B
    __shared__ short slotb_tab[ROWS];                           // byte offset into srows, or -1

    // Minimum possible candidate input row for this block (known a priori).
    const int hb = ((oh0 - 1 - dy) >> 1) - 1;

    // ---- row map: all threads compute all ROWS redundantly (no divergence).
    unsigned usedmask = 0;          // bit (ih - hb) set if input row ih is referenced
    int my_ih = -1;                 // thread tid<ROWS captures row tid's ih
    #pragma unroll
    for (int r = 0; r < ROWS; ++r) {
        int oh = oh0 + r;
        int h0 = (oh - 1 - dy) >> 1;
        int ih = -1;
        #pragma unroll
        for (int d = -1; d <= 1; ++d) {
            int h = h0 + d;
            if (h < 0 || h >= IN_H) continue;
            int f = (int)floorf(((float)h + 0.5f + jy) * 2.0f);  // identical fp32 ops as ref
            f = f < 0 ? 0 : (f > OUT_H - 1 ? OUT_H - 1 : f);
            if (f == oh) ih = h;              // last match wins (np semantics)
        }
        if (ih >= 0) usedmask |= 1u << (ih - hb);
        if (tid == r) my_ih = ih;
    }
    if (tid < ROWS)
        slotb_tab[tid] = (my_ih < 0) ? (short)-1
                                     : (short)((my_ih - hb) * (IN_W * 4));

    // ---- column table: iw_tab[ow] = input col scattering to ow, or -1
    for (int ow = tid; ow < OUT_W; ow += 256) {
        int w0 = (ow - 1 - dx) >> 1;
        short iw = -1;
        #pragma unroll
        for (int d = -1; d <= 1; ++d) {
            int w = w0 + d;
            if (w < 0 || w >= IN_W) continue;
            int f = (int)floorf(((float)w + 0.5f + jx) * 2.0f);
            f = f < 0 ? 0 : (f > OUT_W - 1 ? OUT_W - 1 : f);
            if (f == ow) iw = (short)w;
        }
        iw_tab[ow] = iw;
    }

    // ---- stage referenced input rows into LDS (coalesced float4 loads)
    const floatx4* __restrict__ in4 =
        (const floatx4*)(in + (size_t)(b * CH + c) * IN_H * IN_W);
    floatx4* __restrict__ srows4 = (floatx4*)srows;
    #pragma unroll
    for (int k = 0; k < SLOTS * IN_W4 / 256 + 1; ++k) {   // 7 iterations covers 1680
        int q = k * 256 + tid;
        if (q < SLOTS * IN_W4) {
            int slot = q / IN_W4;                          // const div -> magic mul
            if ((usedmask >> slot) & 1u)                   // only rows actually referenced
                srows4[q] = in4[(size_t)(hb + slot) * IN_W4 + (q - slot * IN_W4)];
        }
    }
    __syncthreads();

    floatx4* __restrict__ outbase =
        (floatx4*)(out + ((size_t)(b * CH + c) * OUT_H + oh0) * OUT_W);
    const char* __restrict__ srows_b = (const char*)srows;

    #pragma unroll
    for (int it = 0; it < NIT; ++it) {
        int pos = it * 256 + tid;
        int r   = pos / OW4;                  // const div -> magic mul
        int ow4 = pos - r * OW4;
        int slotb = slotb_tab[r];             // ds_read_i16 (byte offset or -1)
        floatx4 v = (floatx4)(0.0f);
        if (slotb >= 0) {                     // wave-uniform except at row seams
            const char* rowb = srows_b + slotb;
            short4 s = reinterpret_cast<const short4*>(iw_tab)[ow4];  // ds_read_b64
            if (s.x >= 0) v.x = *(const float*)(rowb + ((int)s.x << 2));
            if (s.y >= 0) v.y = *(const float*)(rowb + ((int)s.y << 2));
            if (s.z >= 0) v.z = *(const float*)(rowb + ((int)s.z << 2));
            if (s.w >= 0) v.w = *(const float*)(rowb + ((int)s.w << 2));
        }
        __builtin_nontemporal_store(v, &outbase[(size_t)r * OW4 + ow4]);
    }
}

extern "C" void kernel_launch(void* const* d_in, const int* in_sizes, int n_in,
                              void* d_out, int out_size, void* d_ws, size_t ws_size,
                              hipStream_t stream) {
    const float* in     = (const float*)d_in[0];   // [8,16,540,960] fp32
    const float* jitter = (const float*)d_in[1];   // [8,2,1,1] fp32
    float* out          = (float*)d_out;           // [8,16,1080,1920] fp32

    dim3 block(256);
    dim3 grid(OUT_H / ROWS, CH, BATCH);            // 135 x 16 x 8 = 17280 blocks
    hipLaunchKernelGGL(ZeroUpsample_kernel, grid, block, 0, stream,
                       in, jitter, out);
}